// Round 2
// baseline (53611.572 us; speedup 1.0000x reference)
//
#include <hip/hip_runtime.h>
#include <cstddef>

__device__ __forceinline__ float sigm(float x) { return 1.f / (1.f + __expf(-x)); }
__device__ __forceinline__ float tanh_(float x) { return 1.f - 2.f / (__expf(2.f * x) + 1.f); }

#define AGLD(p)    __hip_atomic_load((p),  __ATOMIC_RELAXED, __HIP_MEMORY_SCOPE_AGENT)
#define AGST(p, v) __hip_atomic_store((p), (v), __ATOMIC_RELAXED, __HIP_MEMORY_SCOPE_AGENT)
#define AGADD(p,v) __hip_atomic_fetch_add((p), (v), __ATOMIC_RELAXED, __HIP_MEMORY_SCOPE_AGENT)

// 16-wide fp32 dot block: accumulates into a0..a3 (declared by caller)
#define DOT16(wp, hp, kk) do { \
    float4 w0_ = *(const float4*)((wp) + (kk));      float4 x0_ = *(const float4*)((hp) + (kk)); \
    float4 w1_ = *(const float4*)((wp) + (kk) + 4);  float4 x1_ = *(const float4*)((hp) + (kk) + 4); \
    float4 w2_ = *(const float4*)((wp) + (kk) + 8);  float4 x2_ = *(const float4*)((hp) + (kk) + 8); \
    float4 w3_ = *(const float4*)((wp) + (kk) + 12); float4 x3_ = *(const float4*)((hp) + (kk) + 12); \
    a0 = fmaf(w0_.x, x0_.x, a0); a0 = fmaf(w0_.y, x0_.y, a0); a0 = fmaf(w0_.z, x0_.z, a0); a0 = fmaf(w0_.w, x0_.w, a0); \
    a1 = fmaf(w1_.x, x1_.x, a1); a1 = fmaf(w1_.y, x1_.y, a1); a1 = fmaf(w1_.z, x1_.z, a1); a1 = fmaf(w1_.w, x1_.w, a1); \
    a2 = fmaf(w2_.x, x2_.x, a2); a2 = fmaf(w2_.y, x2_.y, a2); a2 = fmaf(w2_.z, x2_.z, a2); a2 = fmaf(w2_.w, x2_.w, a2); \
    a3 = fmaf(w3_.x, x3_.x, a3); a3 = fmaf(w3_.y, x3_.y, a3); a3 = fmaf(w3_.z, x3_.z, a3); a3 = fmaf(w3_.w, x3_.w, a3); \
  } while (0)

// ---------------- K1: embed = relu(inputs @ W_e^T + b_e), layout [s][b][e] ----------------
__global__ __launch_bounds__(256) void k_embed(
    const float* __restrict__ inp, const float* __restrict__ We,
    const float* __restrict__ be, float* __restrict__ emb)
{
  __shared__ float sA[32 * 68];
  __shared__ float sW[32 * 132];
  const int tid = threadIdx.x;
  const int b  = blockIdx.x >> 4;
  const int s0 = (blockIdx.x & 15) << 6;
  float acc[4][8];
#pragma unroll
  for (int i = 0; i < 4; ++i)
#pragma unroll
    for (int j = 0; j < 8; ++j) acc[i][j] = 0.f;
  const int m4 = (tid & 15) << 2;
  const int e8 = (tid >> 4) << 3;
  const float* Ab = inp + ((size_t)(b << 10) + s0) * 1024;
  const int ms = tid >> 2, kq = tid & 3;
  const int es = tid >> 1, kq2 = tid & 1;
  for (int k0 = 0; k0 < 1024; k0 += 32) {
    __syncthreads();
    {
      const float* src = Ab + (size_t)ms * 1024 + k0 + (kq << 3);
      float4 v0 = *(const float4*)(src);
      float4 v1 = *(const float4*)(src + 4);
      int kb = kq << 3;
      sA[(kb+0)*68+ms] = v0.x; sA[(kb+1)*68+ms] = v0.y;
      sA[(kb+2)*68+ms] = v0.z; sA[(kb+3)*68+ms] = v0.w;
      sA[(kb+4)*68+ms] = v1.x; sA[(kb+5)*68+ms] = v1.y;
      sA[(kb+6)*68+ms] = v1.z; sA[(kb+7)*68+ms] = v1.w;
    }
    {
      const float* src = We + (size_t)es * 1024 + k0 + (kq2 << 4);
#pragma unroll
      for (int q = 0; q < 4; ++q) {
        float4 v = *(const float4*)(src + (q << 2));
        int kb = (kq2 << 4) + (q << 2);
        sW[(kb+0)*132+es] = v.x; sW[(kb+1)*132+es] = v.y;
        sW[(kb+2)*132+es] = v.z; sW[(kb+3)*132+es] = v.w;
      }
    }
    __syncthreads();
#pragma unroll 4
    for (int kk = 0; kk < 32; ++kk) {
      float4 a4 = *(const float4*)&sA[kk*68 + m4];
      float4 b0 = *(const float4*)&sW[kk*132 + e8];
      float4 b1 = *(const float4*)&sW[kk*132 + e8 + 4];
      float av[4] = {a4.x, a4.y, a4.z, a4.w};
      float bv[8] = {b0.x, b0.y, b0.z, b0.w, b1.x, b1.y, b1.z, b1.w};
#pragma unroll
      for (int i = 0; i < 4; ++i)
#pragma unroll
        for (int j = 0; j < 8; ++j) acc[i][j] = fmaf(av[i], bv[j], acc[i][j]);
    }
  }
#pragma unroll
  for (int i = 0; i < 4; ++i) {
    int s = s0 + m4 + i;
#pragma unroll
    for (int j = 0; j < 8; ++j) {
      float v = acc[i][j] + be[e8 + j];
      emb[((size_t)(s << 5) + b) * 128 + e8 + j] = v > 0.f ? v : 0.f;
    }
  }
}

// ---------------- K2: a = relu(embed @ Wa1^T + ba1) @ Wa2^T + ba2, layout [s*32+b][3] ----------------
__global__ __launch_bounds__(256) void k_attn(
    const float* __restrict__ emb, const float* __restrict__ Wa1,
    const float* __restrict__ ba1, const float* __restrict__ Wa2,
    const float* __restrict__ ba2, float* __restrict__ aw)
{
  __shared__ float sE[2 * 128];
  __shared__ float sH[2 * 128];
  const int tid = threadIdx.x;
  const int rs0 = blockIdx.x * 2;
  sE[tid] = emb[(size_t)rs0 * 128 + tid];
  __syncthreads();
  const int half = tid >> 7, j = tid & 127;
  const float* w = Wa1 + j * 128;
  const float* e = sE + half * 128;
  float a0 = 0.f, a1 = 0.f, a2 = 0.f, a3 = 0.f;
  for (int k = 0; k < 128; k += 16) DOT16(w, e, k);
  float h = (a0 + a1) + (a2 + a3) + ba1[j];
  sH[half * 128 + j] = h > 0.f ? h : 0.f;
  __syncthreads();
  if (tid < 6) {
    int hh = tid / 3, l = tid % 3;
    const float* w2 = Wa2 + l * 128;
    const float* hv = sH + hh * 128;
    float s = 0.f;
    for (int k = 0; k < 128; ++k) s = fmaf(w2[k], hv[k], s);
    aw[(size_t)(rs0 + hh) * 3 + l] = s + ba2[l];
  }
}

// ---------------- K2b: softmax over time (axis s) per (b, l), in-place ----------------
__global__ __launch_bounds__(256) void k_softmax(float* __restrict__ aw)
{
  __shared__ float red[256];
  const int b = blockIdx.x / 3, l = blockIdx.x % 3;
  const int tid = threadIdx.x;
  float v[4];
#pragma unroll
  for (int i = 0; i < 4; ++i) {
    int s = tid + i * 256;
    v[i] = aw[(size_t)(s * 32 + b) * 3 + l];
  }
  float mx = fmaxf(fmaxf(v[0], v[1]), fmaxf(v[2], v[3]));
  red[tid] = mx;
  __syncthreads();
  for (int off = 128; off > 0; off >>= 1) {
    if (tid < off) red[tid] = fmaxf(red[tid], red[tid + off]);
    __syncthreads();
  }
  mx = red[0];
  __syncthreads();
  float sm = 0.f;
#pragma unroll
  for (int i = 0; i < 4; ++i) sm += __expf(v[i] - mx);
  red[tid] = sm;
  __syncthreads();
  for (int off = 128; off > 0; off >>= 1) {
    if (tid < off) red[tid] += red[tid + off];
    __syncthreads();
  }
  float inv = 1.f / red[0];
#pragma unroll
  for (int i = 0; i < 4; ++i) {
    int s = tid + i * 256;
    aw[(size_t)(s * 32 + b) * 3 + l] = __expf(v[i] - mx) * inv;
  }
}

// ---------------- K_prep: repack Wih_d (516-stride, aligned) + pre-summed biases ----------------
__global__ __launch_bounds__(256) void k_prep(
    const float* __restrict__ Wih_d,
    const float* __restrict__ bih_e, const float* __restrict__ bhh_e,
    const float* __restrict__ bih_d, const float* __restrict__ bhh_d,
    float* __restrict__ wdpack, float* __restrict__ bsum_e, float* __restrict__ bsum_d)
{
  const int row = blockIdx.x;           // 2048 rows
  const int tid = threadIdx.x;
  for (int q = tid; q < 516; q += 256) {
    float v = 0.f;
    if (q < 512)      v = Wih_d[(size_t)row * 513 + 1 + q];   // ctx part
    else if (q == 512) v = Wih_d[(size_t)row * 513];          // p coefficient
    wdpack[(size_t)row * 516 + q] = v;
  }
  if (tid == 0) {
    bsum_e[row] = bih_e[row] + bhh_e[row];
    bsum_d[row] = bih_d[row] + bhh_d[row];
  }
}

// ---------------- K_init: initial states + barrier/pflag zero ----------------
__global__ __launch_bounds__(256) void k_init(
    const float* __restrict__ eh0, const float* __restrict__ dh0,
    const float* __restrict__ bo2,
    float* __restrict__ heb, float* __restrict__ hdb,
    float* __restrict__ out, unsigned* __restrict__ bar)
{
  const int i = blockIdx.x * 256 + threadIdx.x;   // 32768 threads
  if (i < 16384) {
    int k = i & 511;
    heb[16384 + i] = eh0[k];   // heb slot 1 holds h_e(-1)
    hdb[16384 + i] = dh0[k];   // hdb slot 1 holds h_d(-1)  (read at iter 1)
  }
  out[i] = bo2[0];
  if (i < 1024) bar[i] = 0u;
}

// ---------------- group barrier: 64 wgs, two-level counter, UC atomics ----------------
__device__ __forceinline__ void groupbar(unsigned* gbar, int r, unsigned gen)
{
  __builtin_amdgcn_s_waitcnt(0);     // drain this wave's stores/atomics
  __syncthreads();
  if (threadIdx.x == 0) {
    asm volatile("" ::: "memory");
    unsigned old = AGADD(gbar + ((r >> 3) << 4), 1u);
    if (old == (gen << 3) - 1u)          // last of this sub-group of 8 wgs
      (void)AGADD(gbar + 128, 1u);
    while (AGLD(gbar + 128) < (gen << 3))
      __builtin_amdgcn_s_sleep(1);
    asm volatile("" ::: "memory");
  }
  __syncthreads();
}

// ---------------- K_persist: single-barrier-per-iteration pipeline ----------------
// wg = (g = blockIdx>>6, r = blockIdx&63). Group g owns batches [g*8, g*8+8); slice r owns
// h-dims [r*8, r*8+8) of BOTH LSTMs. Decoder lags the encoder by one iteration:
//   iter i: enc -> h_e(i), ctx(i);   dec -> h_d(i-1) (from ctx(i-1), h_d(i-2), p(i-2));
//           out-wg (r<8, batch g*8+r) -> p(i-2) from staged h_d(i-2), published w/ flag.
// p enters dec gates LINEARLY (pcoef per row), so cell owners add pcoef*p after a short
// flag-spin that overlaps with everyone's gate compute. ONE group barrier per iteration.
__global__ __launch_bounds__(256) void k_persist(
    const float* __restrict__ emb, const float* __restrict__ aw,
    const int* __restrict__ lens,
    const float* __restrict__ Wih_e, const float* __restrict__ Whh_e,
    const float* __restrict__ Whh_d, const float* __restrict__ wdpack,
    const float* __restrict__ bsum_e, const float* __restrict__ bsum_d,
    const float* __restrict__ ec0, const float* __restrict__ dc0,
    const float* __restrict__ Wo1, const float* __restrict__ bo1,
    const float* __restrict__ Wo2, const float* __restrict__ bo2,
    const float* __restrict__ maskp,
    float* __restrict__ heb, float* __restrict__ hdb,
    float* __restrict__ ctxb, float* __restrict__ out,
    unsigned* __restrict__ bar)
{
  __shared__ float sHe[8 * 516];   // h_e(i-1), 516-stride -> per-batch lanes hit distinct banks
  __shared__ float sCtx[8 * 516];  // ctx(i-1)
  __shared__ float sHd[8 * 516];   // h_d(i-2)
  __shared__ float sEmb[8 * 132];
  __shared__ float sGe[256], sGd[256];
  __shared__ float sRed[4];

  const int tid = threadIdx.x;
  const int g = blockIdx.x >> 6;        // batch group 0..3
  const int r = blockIdx.x & 63;        // row slice 0..63
  const int rr = tid >> 3;              // gate-row within slice 0..31 (gamma*8 + d)
  const int bb = tid & 7;               // batch within group 0..7
  const int grow = ((rr >> 3) << 9) + (r << 3) + (rr & 7);
  const int gb8 = g << 3;

  unsigned* gbar  = bar + g * 160;
  unsigned* pflag = bar + 768;          // pflag[b*8], 32B apart

  const float be_row = bsum_e[grow];
  const float bd_row = bsum_d[grow];
  const float bo2v = bo2[0];

  // cell-state registers: tid < 64 owns (dim = r*8 + tid>>3, batch = gb8 + (tid&7))
  float c_e = 0.f, c_d = 0.f, hm1 = 0.f, hm2 = 0.f;
  float pc0 = 0.f, pc1 = 0.f, pc2 = 0.f, pc3 = 0.f;
  int len_b = 0;
  if (tid < 64) {
    int dim = (r << 3) + (tid >> 3);
    c_e = ec0[dim];
    c_d = dc0[dim];
    len_b = lens[gb8 + (tid & 7)];
    pc0 = wdpack[(size_t)(0 * 512 + dim) * 516 + 512];
    pc1 = wdpack[(size_t)(1 * 512 + dim) * 516 + 512];
    pc2 = wdpack[(size_t)(2 * 512 + dim) * 516 + 512];
    pc3 = wdpack[(size_t)(3 * 512 + dim) * 516 + 512];
  }

  const float* whe = Whh_e + (size_t)grow * 512;
  const float* wie = Wih_e + (size_t)grow * 128;
  const float* whd = Whh_d + (size_t)grow * 512;
  const float* wdc = wdpack + (size_t)grow * 516;
  const float* hX  = sHe  + bb * 516;
  const float* hC  = sCtx + bb * 516;
  const float* hD  = sHd  + bb * 516;
  const float* hE  = sEmb + bb * 132;

  for (int i = 0; i < 1026; ++i) {
    const bool doEnc = (i < 1024);
    const bool doDec = (i >= 1) && (i < 1025);
    const bool doOut = (i >= 2);

    // ---- stage: h_e(i-1) [slot (i+1)&1], ctx(i-1) [slot (i+1)&1], h_d(i-2) [slot i&1] ----
    {
      const float* hep = heb  + (size_t)((i + 1) & 1) * 16384 + (size_t)gb8 * 512;
      const float* cpp = ctxb + (size_t)((i + 1) & 1) * 16384 + (size_t)gb8 * 512;
      const float* hdp = hdb  + (size_t)(i & 1) * 16384 + (size_t)gb8 * 512;
      float vHe[16], vC[16], vHd[16];
#pragma unroll
      for (int j = 0; j < 16; ++j) {
        vHe[j] = AGLD(hep + tid + j * 256);
        vC[j]  = AGLD(cpp + tid + j * 256);
        vHd[j] = AGLD(hdp + tid + j * 256);
      }
      float4 ev = {0.f, 0.f, 0.f, 0.f};
      if (doEnc)
        ev = *(const float4*)(emb + (size_t)(i * 32 + gb8 + (tid >> 5)) * 128 + ((tid & 31) << 2));
#pragma unroll
      for (int j = 0; j < 16; ++j) {
        int ii = tid + j * 256, bi = ii >> 9, kk = ii & 511;
        sHe [bi * 516 + kk] = vHe[j];
        sCtx[bi * 516 + kk] = vC[j];
        sHd [bi * 516 + kk] = vHd[j];
      }
      if (doEnc)
        *(float4*)(sEmb + (tid >> 5) * 132 + ((tid & 31) << 2)) = ev;
    }
    __syncthreads();

    // ---- out-MLP duty FIRST (r<8; batch gb8+r): p(i-2) from sHd = h_d(i-2) ----
    if (r < 8 && doOut) {
      const int ob = gb8 + r;
      const int e2 = tid << 1;
      const float* w0 = Wo1 + (size_t)e2 * 512;
      const float* hd = sHd + r * 516;
      float a0 = 0.f, a1 = 0.f, a2 = 0.f, a3 = 0.f;
#pragma unroll 4
      for (int k = 0; k < 512; k += 8) {
        float4 x0 = *(const float4*)(hd + k), x1 = *(const float4*)(hd + k + 4);
        float4 u0 = *(const float4*)(w0 + k), u1 = *(const float4*)(w0 + k + 4);
        float4 q0 = *(const float4*)(w0 + 512 + k), q1 = *(const float4*)(w0 + 512 + k + 4);
        a0 = fmaf(u0.x,x0.x,a0); a0 = fmaf(u0.y,x0.y,a0); a0 = fmaf(u0.z,x0.z,a0); a0 = fmaf(u0.w,x0.w,a0);
        a1 = fmaf(u1.x,x1.x,a1); a1 = fmaf(u1.y,x1.y,a1); a1 = fmaf(u1.z,x1.z,a1); a1 = fmaf(u1.w,x1.w,a1);
        a2 = fmaf(q0.x,x0.x,a2); a2 = fmaf(q0.y,x0.y,a2); a2 = fmaf(q0.z,x0.z,a2); a2 = fmaf(q0.w,x0.w,a2);
        a3 = fmaf(q1.x,x1.x,a3); a3 = fmaf(q1.y,x1.y,a3); a3 = fmaf(q1.z,x1.z,a3); a3 = fmaf(q1.w,x1.w,a3);
      }
      float d0 = (a0 + a1) + bo1[e2];
      float d1 = (a2 + a3) + bo1[e2 + 1];
      float contrib = (d0 > 0.f ? d0 : 0.f) * Wo2[e2] + (d1 > 0.f ? d1 : 0.f) * Wo2[e2 + 1];
      contrib += __shfl_down(contrib, 32);
      contrib += __shfl_down(contrib, 16);
      contrib += __shfl_down(contrib, 8);
      contrib += __shfl_down(contrib, 4);
      contrib += __shfl_down(contrib, 2);
      contrib += __shfl_down(contrib, 1);
      if ((tid & 63) == 0) sRed[tid >> 6] = contrib;
      __syncthreads();
      if (tid == 0) {
        float p = sRed[0] + sRed[1] + sRed[2] + sRed[3] + bo2v;
        AGST(&out[(size_t)ob * 1024 + (i - 2)], p);
        __builtin_amdgcn_s_waitcnt(0);         // p visible before flag
        AGST(&pflag[ob << 3], (unsigned)i);
      }
    }

    // ---- enc gates: full 640-dot per (row,batch) thread ----
    if (doEnc) {
      float a0 = 0.f, a1 = 0.f, a2 = 0.f, a3 = 0.f;
#pragma unroll 4
      for (int k = 0; k < 512; k += 16) DOT16(whe, hX, k);
#pragma unroll
      for (int k = 0; k < 128; k += 16) DOT16(wie, hE, k);
      sGe[(rr << 3) + bb] = (a0 + a1) + (a2 + a3) + be_row;
    }
    // ---- dec gates (p-independent part): ctx(i-1) + h_d(i-2) ----
    if (doDec) {
      float a0 = 0.f, a1 = 0.f, a2 = 0.f, a3 = 0.f;
#pragma unroll 2
      for (int k = 0; k < 512; k += 16) { DOT16(whd, hD, k); DOT16(wdc, hC, k); }
      sGd[(rr << 3) + bb] = (a0 + a1) + (a2 + a3) + bd_row;
    }
    __syncthreads();

    // ---- cells (wave 0) ----
    if (tid < 64) {
      const int dim = (r << 3) + (tid >> 3);
      const int gb = gb8 + (tid & 7);
      if (doEnc) {
        float gi = sGe[tid], gf = sGe[64 + tid], gg = sGe[128 + tid], go = sGe[192 + tid];
        c_e = sigm(gf) * c_e + sigm(gi) * tanh_(gg);
        float h = sigm(go) * tanh_(c_e);
        AGST(&heb[(size_t)(i & 1) * 16384 + (size_t)gb * 512 + dim], h);
        float hmv = (i < len_b) ? h : 0.f;
        const float* at = aw + (size_t)(i * 32 + gb) * 3;
        float ctx = at[0] * hmv + at[1] * hm1 + at[2] * hm2;
        hm2 = hm1; hm1 = hmv;
        AGST(&ctxb[(size_t)(i & 1) * 16384 + (size_t)gb * 512 + dim], ctx);
      }
      if (doDec) {
        float p = 0.f;
        if (doOut) {   // p(i-2) produced this iteration by the out-wg
          unsigned* fl = &pflag[gb << 3];
          while (AGLD(fl) < (unsigned)i) __builtin_amdgcn_s_sleep(1);
          p = AGLD(&out[(size_t)gb * 1024 + (i - 2)]);
        }
        float gi = sGd[tid]       + pc0 * p;
        float gf = sGd[64 + tid]  + pc1 * p;
        float gg = sGd[128 + tid] + pc2 * p;
        float go = sGd[192 + tid] + pc3 * p;
        c_d = sigm(gf) * c_d + sigm(gi) * tanh_(gg);
        float h = sigm(go) * tanh_(c_d);
        AGST(&hdb[(size_t)((i + 1) & 1) * 16384 + (size_t)gb * 512 + dim], h);  // slot (i-1)&1
      }
    }
    groupbar(gbar, r, (unsigned)(i + 1));
  }

  // ---- mask own chunk: 128 outputs per wg ----
  if (tid < 128) {
    int idx = blockIdx.x * 128 + tid;
    float v = AGLD(&out[idx]);
    out[idx] = v * maskp[idx];
  }
}

extern "C" void kernel_launch(void* const* d_in, const int* in_sizes, int n_in,
                              void* d_out, int out_size, void* d_ws, size_t ws_size,
                              hipStream_t stream)
{
  const float* inp   = (const float*)d_in[0];
  const float* maskp = (const float*)d_in[1];
  const int*   lens  = (const int*)d_in[2];
  const float* We    = (const float*)d_in[3];
  const float* be    = (const float*)d_in[4];
  const float* Wa1   = (const float*)d_in[5];
  const float* ba1   = (const float*)d_in[6];
  const float* Wa2   = (const float*)d_in[7];
  const float* ba2   = (const float*)d_in[8];
  const float* Wih_e = (const float*)d_in[9];
  const float* Whh_e = (const float*)d_in[10];
  const float* bih_e = (const float*)d_in[11];
  const float* bhh_e = (const float*)d_in[12];
  const float* eh0   = (const float*)d_in[13];
  const float* ec0   = (const float*)d_in[14];
  const float* Wih_d = (const float*)d_in[15];
  const float* Whh_d = (const float*)d_in[16];
  const float* bih_d = (const float*)d_in[17];
  const float* bhh_d = (const float*)d_in[18];
  const float* dh0   = (const float*)d_in[19];
  const float* dc0   = (const float*)d_in[20];
  const float* Wo1   = (const float*)d_in[21];
  const float* bo1   = (const float*)d_in[22];
  const float* Wo2   = (const float*)d_in[23];
  const float* bo2   = (const float*)d_in[24];

  float* ws     = (float*)d_ws;
  float* emb    = ws;                     // 4,194,304
  float* aw     = emb + 4194304;          //    98,304
  float* heb    = aw + 98304;             //    32,768 (2 slots)
  float* hdb    = heb + 32768;            //    32,768 (2 slots)
  float* ctxb   = hdb + 32768;            //    32,768 (2 slots)
  float* wdpack = ctxb + 32768;           // 1,056,768 (2048 x 516)
  float* bsum_e = wdpack + 1056768;       //     2,048
  float* bsum_d = bsum_e + 2048;          //     2,048
  unsigned* bar = (unsigned*)(bsum_d + 2048);  // 1,024 (4x160 barrier + pflag @768)
  float* outf = (float*)d_out;

  k_embed<<<512, 256, 0, stream>>>(inp, We, be, emb);
  k_attn<<<16384, 256, 0, stream>>>(emb, Wa1, ba1, Wa2, ba2, aw);
  k_softmax<<<96, 256, 0, stream>>>(aw);
  k_prep<<<2048, 256, 0, stream>>>(Wih_d, bih_e, bhh_e, bih_d, bhh_d,
                                   wdpack, bsum_e, bsum_d);
  k_init<<<128, 256, 0, stream>>>(eh0, dh0, bo2, heb, hdb, outf, bar);

  k_persist<<<256, 256, 0, stream>>>(
      emb, aw, lens,
      Wih_e, Whh_e, Whh_d, wdpack, bsum_e, bsum_d,
      ec0, dc0, Wo1, bo1, Wo2, bo2, maskp,
      heb, hdb, ctxb, outf, bar);
}